// Round 3
// baseline (238.882 us; speedup 1.0000x reference)
//
#include <hip/hip_runtime.h>

// LaneAttention: per-lane MLP score -> per-group(8) softmax -> weighted pool of
// concat(ht, info, future) into out[32768, 192] fp32.
//
// R5: R2/R4 both pinned at 2.35 TB/s HBM regardless of occupancy (37% vs 67%)
// -> not TLP-starved. VGPR_Count=28 showed ~1 load in flight per wave
// (load -> vmcnt(0) -> consume -> next), and phase-2 re-reads of ht/info missed
// L2 (24 MB resident set vs 4 MB/XCD) costing L3 round-trips. Now: one lane
// owns one row end-to-end. 32 float4 loads issued up front (32 KB in flight
// per wave -> HBM saturates on ILP alone), MLP from registers, 8-lane softmax,
// then pooling via in-register shfl_xor butterflies over the 8-lane group --
// phase-2 global re-reads eliminated entirely. fut loads issue before the
// butterfly so their latency hides under ~1.5k VALU ops. Zero LDS, zero
// barriers, every input byte read exactly once, all accesses float4.
// ~230 VGPR / ~8 waves per CU is deliberate: ILP replaces TLP.

__device__ __forceinline__ float4 shxor4(float4 v, int m) {
    float4 r;
    r.x = __shfl_xor(v.x, m);
    r.y = __shfl_xor(v.y, m);
    r.z = __shfl_xor(v.z, m);
    r.w = __shfl_xor(v.w, m);
    return r;
}
__device__ __forceinline__ float4 add4(float4 a, float4 b) {
    return make_float4(a.x + b.x, a.y + b.y, a.z + b.z, a.w + b.w);
}
__device__ __forceinline__ float4 mul4s(float4 a, float s) {
    return make_float4(a.x * s, a.y * s, a.z * s, a.w * s);
}
__device__ __forceinline__ float4 sel4(bool c, float4 a, float4 b) {
    return make_float4(c ? a.x : b.x, c ? a.y : b.y, c ? a.z : b.z, c ? a.w : b.w);
}

__global__ __launch_bounds__(256, 2) void lane_attn_kernel(
    const float* __restrict__ ht,     // [M,64]
    const float* __restrict__ info,   // [M,64]
    const float* __restrict__ fut,    // [M,64]
    const float* __restrict__ W1,     // [128,16]
    const float* __restrict__ b1,     // [16]
    const float* __restrict__ W2,     // [16]
    const float* __restrict__ b2,     // [1]
    const int*   __restrict__ seg,    // [M]
    float*       __restrict__ out)    // [N_GROUPS,192]
{
    const int row = blockIdx.x * 256 + threadIdx.x;  // one lane = one row
    const int i8  = row & 7;                         // lane within 8-row group

    // ---- stream the row's ht+info into registers: 32 independent float4
    // loads, all issued before first use -> deep vmcnt pipeline.
    float4 x[32];
    const float4* hp = (const float4*)(ht   + (size_t)row * 64);
    const float4* ip = (const float4*)(info + (size_t)row * 64);
#pragma unroll
    for (int f = 0; f < 16; ++f) x[f]      = hp[f];
#pragma unroll
    for (int f = 0; f < 16; ++f) x[16 + f] = ip[f];

    // ---- MLP from registers. W1/b1/W2/b2 indices are wave-uniform -> SGPR.
    float h[16];
#pragma unroll
    for (int j = 0; j < 16; ++j) h[j] = b1[j];
#pragma unroll
    for (int f = 0; f < 32; ++f) {
        const float* wr = W1 + f * 64;   // W1 rows 4f..4f+3, each [16]
#pragma unroll
        for (int j = 0; j < 16; ++j) {
            h[j] = fmaf(x[f].x, wr[ 0 + j], h[j]);
            h[j] = fmaf(x[f].y, wr[16 + j], h[j]);
            h[j] = fmaf(x[f].z, wr[32 + j], h[j]);
            h[j] = fmaf(x[f].w, wr[48 + j], h[j]);
        }
    }
    float score = b2[0];
#pragma unroll
    for (int j = 0; j < 16; ++j)
        score = fmaf(fmaxf(h[j], 0.0f), W2[j], score);

    // ---- softmax across the 8-lane group (xor 1,2,4 stays inside the group)
    float m = score;
    m = fmaxf(m, __shfl_xor(m, 1));
    m = fmaxf(m, __shfl_xor(m, 2));
    m = fmaxf(m, __shfl_xor(m, 4));
    float e = __expf(score - m);
    float s = e;
    s += __shfl_xor(s, 1);
    s += __shfl_xor(s, 2);
    s += __shfl_xor(s, 4);
    const float prob = e / s;

    // ---- issue fut loads NOW: latency hides under the ht/info butterfly.
    float4 xf[16];
    const float4* fp = (const float4*)(fut + (size_t)row * 64);
#pragma unroll
    for (int f = 0; f < 16; ++f) xf[f] = fp[f];

    const int gid = seg[row & ~7];       // 8 lanes share the addr (broadcast)

    // ---- pool ht+info: per float4 slot, weight and butterfly-sum over the
    // 8 lanes; lane i8 keeps slots [4*i8, 4*i8+4) = output cols [16*i8, +16).
    float4 keep[4];
#pragma unroll
    for (int j = 0; j < 4; ++j) keep[j] = make_float4(0.f, 0.f, 0.f, 0.f);
#pragma unroll
    for (int f = 0; f < 32; ++f) {
        float4 y = mul4s(x[f], prob);
        y = add4(y, shxor4(y, 1));
        y = add4(y, shxor4(y, 2));
        y = add4(y, shxor4(y, 4));
        const int  j    = f & 3;             // static index (no scratch)
        const bool mine = ((f >> 2) == i8);
        keep[j] = sel4(mine, y, keep[j]);
    }
    float* og = out + (size_t)gid * 192 + i8 * 16;
    *(float4*)(og +  0) = keep[0];
    *(float4*)(og +  4) = keep[1];
    *(float4*)(og +  8) = keep[2];
    *(float4*)(og + 12) = keep[3];

    // ---- pool fut: lane i8 keeps slots [2*i8, 2*i8+2) = cols 128+[8*i8,+8).
    float4 keep2[2];
#pragma unroll
    for (int j = 0; j < 2; ++j) keep2[j] = make_float4(0.f, 0.f, 0.f, 0.f);
#pragma unroll
    for (int f = 0; f < 16; ++f) {
        float4 y = mul4s(xf[f], prob);
        y = add4(y, shxor4(y, 1));
        y = add4(y, shxor4(y, 2));
        y = add4(y, shxor4(y, 4));
        const int  j    = f & 1;
        const bool mine = ((f >> 1) == i8);
        keep2[j] = sel4(mine, y, keep2[j]);
    }
    float* of = out + (size_t)gid * 192 + 128 + i8 * 8;
    *(float4*)(of + 0) = keep2[0];
    *(float4*)(of + 4) = keep2[1];
}

extern "C" void kernel_launch(void* const* d_in, const int* in_sizes, int n_in,
                              void* d_out, int out_size, void* d_ws, size_t ws_size,
                              hipStream_t stream) {
    const float* ht   = (const float*)d_in[0];
    const float* info = (const float*)d_in[1];
    const float* fut  = (const float*)d_in[2];
    const float* W1   = (const float*)d_in[3];
    const float* b1   = (const float*)d_in[4];
    const float* W2   = (const float*)d_in[5];
    const float* b2   = (const float*)d_in[6];
    const int*   seg  = (const int*)d_in[7];
    float*       out  = (float*)d_out;

    const int M = in_sizes[7];           // 262144 lanes
    const int blocks = M / 256;          // 1024 four-wave blocks, 256 rows each

    lane_attn_kernel<<<blocks, 256, 0, stream>>>(ht, info, fut, W1, b1, W2, b2,
                                                 seg, out);
}

// Round 4
// 215.171 us; speedup vs baseline: 1.1102x; 1.1102x over previous
//
#include <hip/hip_runtime.h>

// LaneAttention: per-lane MLP score -> per-group(8) softmax -> weighted pool of
// concat(ht, info, future) into out[32768, 192] fp32.
//
// R6: R2/R4 pinned at 2.35 TB/s at BOTH 16 and 21 waves/CU -> not occupancy.
// Invariant culprit: phase-1 row-per-lane loads (stride 256B) touch 64 distinct
// cache lines per wave-instruction; the per-CU L1 port / miss-queue is shared
// by all waves, so TLP can't help. R5's in-register fix failed (VGPR cap ->
// compiler reload/spill; 576 ds_bpermute/lane for butterfly pooling).
// Now: stage the block's ht+info tile into LDS with fully-coalesced loads
// (1 KB contiguous per wave-instr, 16/16 lines fully used), run R4's proven
// row-per-lane MLP out of LDS (XOR-swizzled, <=2-way bank access = free),
// phase-2 ht/info re-reads also from LDS; fut stays direct coalesced global.
// W1 stays wave-uniform -> SGPR operands. 256 thr / 64 rows per block; 4 waves
// each do a quarter of the 128-dim reduction; partials meet in padded LDS.
// LDS 53.2 KB -> 3 blocks/CU (12 waves/CU; occupancy proven not the lever).

__global__ __launch_bounds__(256, 3) void lane_attn_kernel(
    const float* __restrict__ ht,     // [M,64]
    const float* __restrict__ info,   // [M,64]
    const float* __restrict__ fut,    // [M,64]
    const float* __restrict__ W1,     // [128,16]
    const float* __restrict__ b1,     // [16]
    const float* __restrict__ W2,     // [16]
    const float* __restrict__ b2,     // [1]
    const int*   __restrict__ seg,    // [M]
    float*       __restrict__ out)    // [N_GROUPS,192]
{
    const int tid  = threadIdx.x;                                   // 0..255
    const int t    = tid & 63;                                      // lane
    const int w    = __builtin_amdgcn_readfirstlane(tid >> 6);      // wave 0..3
    const int base = blockIdx.x * 64;                               // block rows

    // x-tile: 64 rows x 32 16B-slots (slot s<16: ht quad s; s>=16: info quad
    // s-16). Slot stored at s' = s ^ (row&31): per quarter-wave every bank
    // group is hit by exactly 2 lanes on both ds_write_b128 and ds_read_b128
    // (2-way = free, m136).
    __shared__ float4 xtile[64 * 32];       // 32 KB
    // per-wave MLP partials, padded 16->20 floats (t*20 mod 32 has period 8
    // -> 2-way on b128 reads).
    __shared__ float  hpart[4][64][20];     // 20.5 KB

    // ---------------- stage: coalesced global -> swizzled LDS ----------------
    // chunk g = i*256 + tid: (row, s) = (g>>5, g&31). Per wave-instruction:
    // 2 rows x 32 slots = four 256B contiguous runs = 16 fully-used lines.
#pragma unroll
    for (int i = 0; i < 8; ++i) {
        const int g   = i * 256 + tid;
        const int row = g >> 5;
        const int s   = g & 31;
        const float* src = (s < 16)
            ? (ht   + (size_t)(base + row) * 64 + s * 4)
            : (info + (size_t)(base + row) * 64 + (s - 16) * 4);
        xtile[row * 32 + (s ^ (row & 31))] = *(const float4*)src;
    }
    __syncthreads();

    // ------------- phase 1: quarter-row MLP, cols [w*32, w*32+32) -------------
    // W1 row offset is wave-uniform -> scalar loads (SGPR operands on v_fma).
    float h[16];
#pragma unroll
    for (int j = 0; j < 16; ++j) h[j] = 0.0f;

    const float* w1 = W1 + (w * 32) * 16;
#pragma unroll
    for (int k = 0; k < 8; ++k) {
        const int s  = w * 8 + k;                  // slot = x cols [4s, 4s+4)
        const float4 v = xtile[t * 32 + (s ^ (t & 31))];
#pragma unroll
        for (int j = 0; j < 16; ++j) {
            h[j] = fmaf(v.x, w1[(k * 4 + 0) * 16 + j], h[j]);
            h[j] = fmaf(v.y, w1[(k * 4 + 1) * 16 + j], h[j]);
            h[j] = fmaf(v.z, w1[(k * 4 + 2) * 16 + j], h[j]);
            h[j] = fmaf(v.w, w1[(k * 4 + 3) * 16 + j], h[j]);
        }
    }
#pragma unroll
    for (int j4 = 0; j4 < 4; ++j4)
        *(float4*)&hpart[w][t][j4 * 4] =
            make_float4(h[j4*4], h[j4*4+1], h[j4*4+2], h[j4*4+3]);
    __syncthreads();

    // ------------- combine + score + softmax (all waves, row = lane t) -------
    float score = b2[0];
    {
        float acc[16];
#pragma unroll
        for (int j = 0; j < 16; ++j) acc[j] = b1[j];
#pragma unroll
        for (int ww = 0; ww < 4; ++ww) {
#pragma unroll
            for (int j4 = 0; j4 < 4; ++j4) {
                const float4 p = *(const float4*)&hpart[ww][t][j4 * 4];
                acc[j4*4+0] += p.x; acc[j4*4+1] += p.y;
                acc[j4*4+2] += p.z; acc[j4*4+3] += p.w;
            }
        }
#pragma unroll
        for (int j = 0; j < 16; ++j)
            score = fmaf(fmaxf(acc[j], 0.0f), W2[j], score);
    }

    float m = score;
    m = fmaxf(m, __shfl_xor(m, 1));
    m = fmaxf(m, __shfl_xor(m, 2));
    m = fmaxf(m, __shfl_xor(m, 4));
    float e = __expf(score - m);
    float s8 = e;
    s8 += __shfl_xor(s8, 1);
    s8 += __shfl_xor(s8, 2);
    s8 += __shfl_xor(s8, 4);
    const float prob = e / s8;   // lane t holds prob of local row t (all waves)

    // ---------------- phase 2: pooling, 2 groups per wave --------------------
    // ht/info from swizzled LDS (hot); fut direct coalesced global (cold).
    for (int gg = 0; gg < 2; ++gg) {
        const int g2  = w * 2 + gg;          // group index within block (0..7)
        const int r0  = g2 * 8;              // first local row of group
        const int gid = seg[base + r0];      // wave-uniform -> scalar load
        float a0 = 0.0f, a1 = 0.0f, a2 = 0.0f;
#pragma unroll
        for (int i = 0; i < 8; ++i) {
            const int   r  = r0 + i;
            const float p  = __shfl(prob, r);            // row r's prob
            const float* x = (const float*)&xtile[r * 32];
            const int   s0 = ((t >> 2) ^ (r & 31)) * 4 + (t & 3);        // ht col t
            const int   s1 = (((t >> 2) + 16) ^ (r & 31)) * 4 + (t & 3); // info col t
            a0 = fmaf(p, x[s0], a0);
            a1 = fmaf(p, x[s1], a1);
            a2 = fmaf(p, fut[(size_t)(base + r) * 64 + t], a2);
        }
        float* o = out + (size_t)gid * 192;
        o[t]       = a0;
        o[64 + t]  = a1;
        o[128 + t] = a2;
    }
}

extern "C" void kernel_launch(void* const* d_in, const int* in_sizes, int n_in,
                              void* d_out, int out_size, void* d_ws, size_t ws_size,
                              hipStream_t stream) {
    const float* ht   = (const float*)d_in[0];
    const float* info = (const float*)d_in[1];
    const float* fut  = (const float*)d_in[2];
    const float* W1   = (const float*)d_in[3];
    const float* b1   = (const float*)d_in[4];
    const float* W2   = (const float*)d_in[5];
    const float* b2   = (const float*)d_in[6];
    const int*   seg  = (const int*)d_in[7];
    float*       out  = (float*)d_out;

    const int M = in_sizes[7];           // 262144 lanes
    const int blocks = M / 64;           // 4096 blocks, 256 threads, 64 rows

    lane_attn_kernel<<<blocks, 256, 0, stream>>>(ht, info, fut, W1, b1, W2, b2,
                                                 seg, out);
}